// Round 7
// baseline (5887.851 us; speedup 1.0000x reference)
//
#include <hip/hip_runtime.h>
#include <hip/hip_bf16.h>

#define TT 512
#define BB 64
#define II 256
#define HH 1024
#define NWG 256
#define MB 32          // batches per WG
#define NR 32          // packed gate rows per WG (8 j x 4 gates, p = j*4+g)
#define KTOT 1280      // packed weight row: 256 (x) + 1024 (h)
#define ROWB 2048      // bytes per LDS row (1024 bf16)
#define NFLAG 1024     // 2 groups x 128 gt x 4 waves

typedef __bf16 bf16x8 __attribute__((ext_vector_type(8)));
typedef float f32x4 __attribute__((ext_vector_type(4)));
typedef unsigned uint32x4 __attribute__((ext_vector_type(4)));
typedef unsigned uint32x2 __attribute__((ext_vector_type(2)));

__device__ inline uint32x4 ld16_sc1(const void* p) {
  uint32x4 r;
  asm volatile("global_load_dwordx4 %0, %1, off sc1" : "=&v"(r) : "v"(p));
  return r;
}
__device__ inline void st32_sc1(void* p, float v) {
  asm volatile("global_store_dword %0, %1, off sc1" :: "v"(p), "v"(v) : "memory");
}

// ---------------- prep kernels ----------------

__global__ __launch_bounds__(256) void k_cast_inputs(const float* __restrict__ in,
                                                     __hip_bfloat16* __restrict__ outp) {
  int i = (blockIdx.x * 256 + threadIdx.x) * 4;
  float4 v = *reinterpret_cast<const float4*>(in + i);
  outp[i + 0] = __float2bfloat16(v.x);
  outp[i + 1] = __float2bfloat16(v.y);
  outp[i + 2] = __float2bfloat16(v.z);
  outp[i + 3] = __float2bfloat16(v.w);
}

// Packed row p = j*4 + gate (gate order i,f,g,o), cols [0:256)=Wx, [256:1280)=Wh
__global__ __launch_bounds__(256) void k_pack_w(
    const float* __restrict__ wxi, const float* __restrict__ whi,
    const float* __restrict__ wxf, const float* __restrict__ whf,
    const float* __restrict__ wxg, const float* __restrict__ whg,
    const float* __restrict__ wxo, const float* __restrict__ who,
    __hip_bfloat16* __restrict__ Wp) {
  int t = blockIdx.x * 256 + threadIdx.x;   // 0 .. 4096*320
  int p = t / 320;
  int k4 = (t - p * 320) * 4;
  int j = p >> 2, gate = p & 3;
  const float* wx = (gate == 0) ? wxi : (gate == 1) ? wxf : (gate == 2) ? wxg : wxo;
  const float* wh = (gate == 0) ? whi : (gate == 1) ? whf : (gate == 2) ? whg : who;
  float4 v;
  if (k4 < II) v = *reinterpret_cast<const float4*>(wx + (size_t)j * II + k4);
  else         v = *reinterpret_cast<const float4*>(wh + (size_t)j * HH + (k4 - II));
  __hip_bfloat16* o = Wp + (size_t)p * KTOT + k4;
  o[0] = __float2bfloat16(v.x);
  o[1] = __float2bfloat16(v.y);
  o[2] = __float2bfloat16(v.z);
  o[3] = __float2bfloat16(v.w);
}

__global__ __launch_bounds__(256) void k_pack_bias_h0(
    const float* __restrict__ bii, const float* __restrict__ bhi,
    const float* __restrict__ bif, const float* __restrict__ bhf,
    const float* __restrict__ bg,  const float* __restrict__ bhg,
    const float* __restrict__ bio, const float* __restrict__ bho,
    const float* __restrict__ h0, float* __restrict__ biasp,
    __hip_bfloat16* __restrict__ hb, unsigned* __restrict__ flags) {
  int i = blockIdx.x * 256 + threadIdx.x;   // 0..65535
  if (i < 4096) {
    int j = i >> 2, gate = i & 3;
    const float* bi = (gate == 0) ? bii : (gate == 1) ? bif : (gate == 2) ? bg : bio;
    const float* bh = (gate == 0) ? bhi : (gate == 1) ? bhf : (gate == 2) ? bhg : bho;
    biasp[i] = bi[j] + bh[j];
  }
  if (i < NFLAG) flags[i] = 0;
  hb[i] = __float2bfloat16(h0[i]);
}

// ---------------- persistent recurrent kernel ----------------
// R6 structure (proven): 256 WGs x 256 thr. WG (bt,gt): bt=blk>>7 batches
// [bt*32,+32), gt=blk&127 hidden units [gt*8,+8) = packed rows [gt*32,+32).
// Per-wave flags/publish/poll/stage; one __syncthreads per step.
// NEW vs R6 (the one delta): in-loop h staging uses NORMAL cacheable loads
// after a per-wave `buffer_inv sc0 sc1` -> ~16 WGs per XCD share each h image
// through the XCD L2 (MALL traffic 16MB -> ~2MB/step). Requires zero dirty
// L2 lines in the loop: ALL loop global stores are sc1 write-through.

__global__ __launch_bounds__(256, 1) void k_lstm(
    const __hip_bfloat16* __restrict__ xb,
    const __hip_bfloat16* __restrict__ Wp,
    const float* __restrict__ biasp,
    const float* __restrict__ c0,
    __hip_bfloat16* __restrict__ hbuf,    // 2 x (B,H) bf16 ping-pong
    unsigned* __restrict__ flags,         // 2 groups x 128 gt x 4 waves
    float* __restrict__ out)
{
  extern __shared__ __align__(16) char smem[];
  char* Wl = smem;                       // 65536: Wh rows, XOR-swizzled 16B units
  char* Hs = smem + 65536;               // 65536: staged h rows (local batches)
  char* Zx = smem + 131072;              // 5120: per-wave z exchange
  char* Ho = smem + 136192;              // 512: per-wave h bounce (4 x 128B)

  const int tid = threadIdx.x;
  const int lane = tid & 63;
  const int wq = tid >> 6;
  const int bt = blockIdx.x >> 7;        // batch group 0..1
  const int gt = blockIdx.x & 127;       // j tile 0..127
  const int b0 = bt * MB;
  const int r0 = gt * NR;

  const int mh = wq >> 1;                // batch half
  const int nh = wq & 1;                 // row half
  const int l15 = lane & 15;
  const int kqu = lane >> 4;             // 0..3 (16B unit within 32-k chunk)

  // ---- prologue: stage Wh -> Wl (coalesced normal loads, 256 threads) ----
  {
    uint32x4 tmp[16];
#pragma unroll
    for (int q = 0; q < 16; ++q) {
      int row = q * 2 + (tid >> 7);
      int u = tid & 127;
      tmp[q] = *reinterpret_cast<const uint32x4*>(Wp + (size_t)(r0 + row) * KTOT + II + u * 8);
    }
#pragma unroll
    for (int q = 0; q < 16; ++q) {
      int row = q * 2 + (tid >> 7);
      int u = tid & 127;
      *reinterpret_cast<uint32x4*>(Wl + row * ROWB + ((u ^ (row & 7)) << 4)) = tmp[q];
    }
  }

  // ---- x-part weights in registers: wave's 16 rows ----
  bf16x8 wxr[8];
  {
    const __hip_bfloat16* wsrc = Wp + (size_t)(r0 + nh * 16 + l15) * KTOT + kqu * 8;
#pragma unroll
    for (int kk = 0; kk < 8; ++kk)
      wxr[kk] = *reinterpret_cast<const bf16x8*>(wsrc + kk * 32);
  }

  // ---- epilogue cell identity ----
  const int m_e = 4 * kqu + (lane & 3);            // batch offset in wave tile
  const int tq = (lane >> 2) & 3;                  // j offset in wave tile
  const int j_l = nh * 4 + tq;                     // 0..7
  const int b_l = mh * 16 + m_e;                   // 0..31
  const int j_g = gt * 8 + j_l;
  const int b_g = b0 + b_l;
  const float4 bias = *reinterpret_cast<const float4*>(biasp + j_g * 4);
  float c_reg = c0[(size_t)b_g * HH + j_g];

  // ---- fragment geometry ----
  const int am_row = mh * 16 + l15, am_swz = am_row & 7;   // A rows (batches)
  const int bn_row = nh * 16 + l15, bn_swz = bn_row & 7;   // B rows (gate rows)
  char* ZxW = Zx + wq * 1280;
  char* HoW = Ho + wq * 128;

  // ---- prologue: per-wave stage h(0) -> Hs rows [wq*8,+8), coalesced sc1 ----
  {
    uint32x4 tmp[16];
#pragma unroll
    for (int q = 0; q < 16; ++q) {
      int idx = q * 64 + lane;                     // 0..1023
      int rl = wq * 8 + (idx >> 7);
      int u = idx & 127;
      tmp[q] = ld16_sc1(hbuf + (size_t)(b0 + rl) * HH + u * 8);
    }
    asm volatile("s_waitcnt vmcnt(0)" ::: "memory");
    __builtin_amdgcn_sched_barrier(0);
#pragma unroll
    for (int q = 0; q < 16; ++q) {
      int idx = q * 64 + lane;
      int rl = wq * 8 + (idx >> 7);
      int u = idx & 127;
      *reinterpret_cast<uint32x4*>(Hs + rl * ROWB + ((u ^ (rl & 7)) << 4)) = tmp[q];
    }
  }

  // ---- prologue: x-part MFMA for t=0 ----
  const __hip_bfloat16* xrowA = xb + (size_t)(b0 + mh * 16 + l15) * (TT * II) + kqu * 8;
  f32x4 accs[4];
#pragma unroll
  for (int q = 0; q < 4; ++q) accs[q] = (f32x4){0.f, 0.f, 0.f, 0.f};
#pragma unroll
  for (int kk = 0; kk < 8; ++kk) {
    bf16x8 xa = *reinterpret_cast<const bf16x8*>(xrowA + kk * 32);
    accs[kk & 3] = __builtin_amdgcn_mfma_f32_16x16x32_bf16(xa, wxr[kk], accs[kk & 3], 0, 0, 0);
  }

  __syncthreads();

  for (int t = 0; t < TT; ++t) {
    // ---- A: h-part MFMA (x-part already in accs) ----
#pragma unroll
    for (int kk = 0; kk < 32; ++kk) {
      int u = kk * 4 + kqu;
      bf16x8 a = *reinterpret_cast<const bf16x8*>(Hs + am_row * ROWB + ((u ^ am_swz) << 4));
      bf16x8 b = *reinterpret_cast<const bf16x8*>(Wl + bn_row * ROWB + ((u ^ bn_swz) << 4));
      accs[kk & 3] = __builtin_amdgcn_mfma_f32_16x16x32_bf16(a, b, accs[kk & 3], 0, 0, 0);
    }
    f32x4 acc = (accs[0] + accs[1]) + (accs[2] + accs[3]);

    // ---- B: in-wave z exchange via LDS (drains step-A LDS reads too) ----
    *reinterpret_cast<f32x4*>(ZxW + l15 * 80 + kqu * 16) = acc;
    asm volatile("s_waitcnt lgkmcnt(0)" ::: "memory");
    __builtin_amdgcn_sched_barrier(0);
    float zi = *reinterpret_cast<const float*>(ZxW + (4 * tq + 0) * 80 + m_e * 4) + bias.x;
    float zf = *reinterpret_cast<const float*>(ZxW + (4 * tq + 1) * 80 + m_e * 4) + bias.y;
    float zg = *reinterpret_cast<const float*>(ZxW + (4 * tq + 2) * 80 + m_e * 4) + bias.z;
    float zo = *reinterpret_cast<const float*>(ZxW + (4 * tq + 3) * 80 + m_e * 4) + bias.w;

    float ig = 1.f / (1.f + __expf(-zi));
    float fg = 1.f / (1.f + __expf(-zf));
    float gg = 2.f / (1.f + __expf(-2.f * zg)) - 1.f;
    float og = 1.f / (1.f + __expf(-zo));
    c_reg = fg * c_reg + ig * gg;
    float tc = 2.f / (1.f + __expf(-2.f * c_reg)) - 1.f;
    float h = og * tc;

    if (t == TT - 1) {
      st32_sc1(out + (size_t)b_g * (TT * HH) + (size_t)t * HH + j_g, h);
      st32_sc1(out + (size_t)BB * TT * HH + (size_t)b_g * HH + j_g, h);
      st32_sc1(out + (size_t)BB * TT * HH + BB * HH + (size_t)b_g * HH + j_g, c_reg);
      break;
    }

    // ---- C: h -> wave-local Ho bounce, publish 8B sc1, per-wave flag ----
    __hip_bfloat16 hb16 = __float2bfloat16(h);
    *reinterpret_cast<unsigned short*>(HoW + m_e * 8 + tq * 2) =
        *reinterpret_cast<unsigned short*>(&hb16);
    asm volatile("s_waitcnt lgkmcnt(0)" ::: "memory");
    __builtin_amdgcn_sched_barrier(0);

    const int nxt = (t + 1) & 1;
    if (lane < 16) {
      uint32x2 hv = *reinterpret_cast<const uint32x2*>(HoW + lane * 8);
      __hip_bfloat16* dst = hbuf + (size_t)nxt * (BB * HH)
                          + (size_t)(b0 + mh * 16 + lane) * HH + gt * 8 + nh * 4;
      asm volatile("global_store_dwordx2 %0, %1, off sc1" :: "v"(dst), "v"(hv) : "memory");
    }
    asm volatile("s_waitcnt vmcnt(0)" ::: "memory");
    if (lane == 0) {
      unsigned gen = (unsigned)t + 1u;
      asm volatile("global_store_dword %0, %1, off sc1"
                   :: "v"(flags + bt * 512 + gt * 4 + wq), "v"(gen) : "memory");
    }

    // ---- D: poll-window work: out store (sc1) + x(t+1)-part MFMA ----
    st32_sc1(out + (size_t)b_g * (TT * HH) + (size_t)t * HH + j_g, h);
#pragma unroll
    for (int q = 0; q < 4; ++q) accs[q] = (f32x4){0.f, 0.f, 0.f, 0.f};
    {
      const __hip_bfloat16* xp = xrowA + (size_t)(t + 1) * II;
#pragma unroll
      for (int kk = 0; kk < 8; ++kk) {
        bf16x8 xa = *reinterpret_cast<const bf16x8*>(xp + kk * 32);
        accs[kk & 3] = __builtin_amdgcn_mfma_f32_16x16x32_bf16(xa, wxr[kk], accs[kk & 3], 0, 0, 0);
      }
    }

    // ---- E: every wave polls its group's 512 flags (8 per lane) ----
    {
      const unsigned target = (unsigned)t + 1u;
      const unsigned* fp = flags + bt * 512 + lane * 8;
      uint32x4 f1, f2;
      int ok;
      do {
        asm volatile("global_load_dwordx4 %0, %2, off sc1\n\t"
                     "global_load_dwordx4 %1, %3, off sc1\n\t"
                     "s_waitcnt vmcnt(0)"
                     : "=&v"(f1), "=&v"(f2) : "v"(fp), "v"(fp + 4) : "memory");
        ok = (f1.x >= target) && (f1.y >= target) && (f1.z >= target) && (f1.w >= target)
          && (f2.x >= target) && (f2.y >= target) && (f2.z >= target) && (f2.w >= target);
      } while (!__all(ok));
    }

    // ---- E2: discard stale (clean) h lines in L1 + this XCD's L2 ----
    asm volatile("buffer_inv sc0 sc1" ::: "memory");
    asm volatile("s_waitcnt vmcnt(0)" ::: "memory");
    __builtin_amdgcn_sched_barrier(0);

    // ---- F: per-wave stage h(t+1) -> Hs rows [wq*8,+8), NORMAL cacheable ----
    {
      uint32x4 tmp[16];
      const __hip_bfloat16* hsrc = hbuf + (size_t)nxt * (BB * HH);
#pragma unroll
      for (int q = 0; q < 16; ++q) {
        int idx = q * 64 + lane;
        int rl = wq * 8 + (idx >> 7);
        int u = idx & 127;
        tmp[q] = *reinterpret_cast<const uint32x4*>(hsrc + (size_t)(b0 + rl) * HH + u * 8);
      }
#pragma unroll
      for (int q = 0; q < 16; ++q) {
        int idx = q * 64 + lane;
        int rl = wq * 8 + (idx >> 7);
        int u = idx & 127;
        *reinterpret_cast<uint32x4*>(Hs + rl * ROWB + ((u ^ (rl & 7)) << 4)) = tmp[q];
      }
    }
    __syncthreads();                     // stage -> fragment-read handoff
  }
}

// ---------------- launcher ----------------

extern "C" void kernel_launch(void* const* d_in, const int* in_sizes, int n_in,
                              void* d_out, int out_size, void* d_ws, size_t ws_size,
                              hipStream_t stream) {
  (void)in_sizes; (void)n_in; (void)out_size; (void)ws_size;
  const float* inputs = (const float*)d_in[0];
  const float* h0 = (const float*)d_in[1];
  const float* c0 = (const float*)d_in[2];
  const float* w_ii = (const float*)d_in[3];
  const float* w_hi = (const float*)d_in[4];
  const float* b_ii = (const float*)d_in[5];
  const float* b_hi = (const float*)d_in[6];
  const float* w_if = (const float*)d_in[7];
  const float* w_hf = (const float*)d_in[8];
  const float* b_if = (const float*)d_in[9];
  const float* b_hf = (const float*)d_in[10];
  const float* w_io = (const float*)d_in[11];
  const float* w_ho = (const float*)d_in[12];
  const float* b_io = (const float*)d_in[13];
  const float* b_ho = (const float*)d_in[14];
  const float* w_ig = (const float*)d_in[15];
  const float* w_hg = (const float*)d_in[16];
  const float* b_ig = (const float*)d_in[17];
  const float* b_hg = (const float*)d_in[18];

  char* ws = (char*)d_ws;
  __hip_bfloat16* xb    = (__hip_bfloat16*)ws;                    // 16,777,216 B
  __hip_bfloat16* Wp    = (__hip_bfloat16*)(ws + 16777216);       // 10,485,760 B
  float*          biasp = (float*)(ws + 27262976);                // 16,384 B
  __hip_bfloat16* hbuf  = (__hip_bfloat16*)(ws + 27279360);       // 262,144 B
  unsigned*       flags = (unsigned*)(ws + 27541504);             // 4,096 B
  float* out = (float*)d_out;

  k_cast_inputs<<<8192, 256, 0, stream>>>(inputs, xb);
  k_pack_w<<<5120, 256, 0, stream>>>(w_ii, w_hi, w_if, w_hf, w_ig, w_hg, w_io, w_ho, Wp);
  k_pack_bias_h0<<<256, 256, 0, stream>>>(b_ii, b_hi, b_if, b_hf, b_ig, b_hg,
                                          b_io, b_ho, h0, biasp, hbuf, flags);

  const int lds_bytes = 136704;
  hipFuncSetAttribute((const void*)k_lstm,
                      hipFuncAttributeMaxDynamicSharedMemorySize, lds_bytes);
  void* args[] = {(void*)&xb, (void*)&Wp, (void*)&biasp, (void*)&c0,
                  (void*)&hbuf, (void*)&flags, (void*)&out};
  hipLaunchCooperativeKernel((void*)k_lstm, dim3(NWG), dim3(256), args,
                             lds_bytes, stream);
}

// Round 8
// 2180.563 us; speedup vs baseline: 2.7002x; 2.7002x over previous
//
#include <hip/hip_runtime.h>
#include <hip/hip_bf16.h>

#define TT 512
#define BB 64
#define II 256
#define HH 1024
#define NWG 256
#define MB 16          // batches per WG (4 batch groups)
#define NJ 16          // hidden units per WG (64 j-tiles)
#define NR 64          // packed gate rows per WG (16 j x 4 gates, p = j*4+g)
#define KTOT 1280      // packed weight row: 256 (x) + 1024 (h)
#define WU 120         // Wh k-units (16B) kept in LDS; units 120..127 in regs
#define WROWB 1920     // bytes per Wl row (120 units)
#define HROWB 2048     // bytes per Hs row (128 units)
#define NFLAG 1024     // 4 groups x 64 gt x 4 waves

typedef __bf16 bf16x8 __attribute__((ext_vector_type(8)));
typedef float f32x4 __attribute__((ext_vector_type(4)));
typedef unsigned uint32x4 __attribute__((ext_vector_type(4)));
typedef unsigned uint32x2 __attribute__((ext_vector_type(2)));

__device__ inline uint32x4 ld16_sc1(const void* p) {
  uint32x4 r;
  asm volatile("global_load_dwordx4 %0, %1, off sc1" : "=&v"(r) : "v"(p));
  return r;
}

// ---------------- prep kernels ----------------

__global__ __launch_bounds__(256) void k_cast_inputs(const float* __restrict__ in,
                                                     __hip_bfloat16* __restrict__ outp) {
  int i = (blockIdx.x * 256 + threadIdx.x) * 4;
  float4 v = *reinterpret_cast<const float4*>(in + i);
  outp[i + 0] = __float2bfloat16(v.x);
  outp[i + 1] = __float2bfloat16(v.y);
  outp[i + 2] = __float2bfloat16(v.z);
  outp[i + 3] = __float2bfloat16(v.w);
}

// Packed row p = j*4 + gate (gate order i,f,g,o), cols [0:256)=Wx, [256:1280)=Wh
__global__ __launch_bounds__(256) void k_pack_w(
    const float* __restrict__ wxi, const float* __restrict__ whi,
    const float* __restrict__ wxf, const float* __restrict__ whf,
    const float* __restrict__ wxg, const float* __restrict__ whg,
    const float* __restrict__ wxo, const float* __restrict__ who,
    __hip_bfloat16* __restrict__ Wp) {
  int t = blockIdx.x * 256 + threadIdx.x;   // 0 .. 4096*320
  int p = t / 320;
  int k4 = (t - p * 320) * 4;
  int j = p >> 2, gate = p & 3;
  const float* wx = (gate == 0) ? wxi : (gate == 1) ? wxf : (gate == 2) ? wxg : wxo;
  const float* wh = (gate == 0) ? whi : (gate == 1) ? whf : (gate == 2) ? whg : who;
  float4 v;
  if (k4 < II) v = *reinterpret_cast<const float4*>(wx + (size_t)j * II + k4);
  else         v = *reinterpret_cast<const float4*>(wh + (size_t)j * HH + (k4 - II));
  __hip_bfloat16* o = Wp + (size_t)p * KTOT + k4;
  o[0] = __float2bfloat16(v.x);
  o[1] = __float2bfloat16(v.y);
  o[2] = __float2bfloat16(v.z);
  o[3] = __float2bfloat16(v.w);
}

__global__ __launch_bounds__(256) void k_pack_bias_h0(
    const float* __restrict__ bii, const float* __restrict__ bhi,
    const float* __restrict__ bif, const float* __restrict__ bhf,
    const float* __restrict__ bg,  const float* __restrict__ bhg,
    const float* __restrict__ bio, const float* __restrict__ bho,
    const float* __restrict__ h0, float* __restrict__ biasp,
    __hip_bfloat16* __restrict__ hb, unsigned* __restrict__ flags) {
  int i = blockIdx.x * 256 + threadIdx.x;   // 0..65535
  if (i < 4096) {
    int j = i >> 2, gate = i & 3;
    const float* bi = (gate == 0) ? bii : (gate == 1) ? bif : (gate == 2) ? bg : bio;
    const float* bh = (gate == 0) ? bhi : (gate == 1) ? bhf : (gate == 2) ? bhg : bho;
    biasp[i] = bi[j] + bh[j];
  }
  if (i < NFLAG) flags[i] = 0;
  hb[i] = __float2bfloat16(h0[i]);
}

// ---------------- persistent recurrent kernel ----------------
// R6 protocol (proven) + retile MB=16/NJ=16: 256 WGs x 256 thr. WG (bt,gt):
// bt=blk>>6 batches [bt*16,+16), gt=blk&63 hidden units [gt*16,+16) = packed
// rows [gt*64,+64). Wave wq owns rows [gt*64+wq*16,+16) (16x16 output tile,
// all 16 batches). Wh in LDS for k-units 0..119 + per-lane reg tail (120..127);
// Wx in regs. h staged in LDS via coalesced sc1 (32KB/WG -> 8MB/step, was 16).
// Per-wave flags/publish/poll/stage; one __syncthreads per step.

__global__ __launch_bounds__(256, 1) void k_lstm(
    const __hip_bfloat16* __restrict__ xb,
    const __hip_bfloat16* __restrict__ Wp,
    const float* __restrict__ biasp,
    const float* __restrict__ c0,
    __hip_bfloat16* __restrict__ hbuf,    // 2 x (B,H) bf16 ping-pong
    unsigned* __restrict__ flags,         // 4 groups x 64 gt x 4 waves
    float* __restrict__ out)
{
  extern __shared__ __align__(16) char smem[];
  char* Wl = smem;                        // 122880: Wh 64 rows x 120 units, XOR-swz
  char* Hs = smem + 122880;               // 32768: staged h, 16 rows x 128 units
  char* Zx = smem + 155648;               // 5120: per-wave z exchange
  char* Ho = smem + 160768;               // 512: per-wave h bounce (4 x 128B)

  const int tid = threadIdx.x;
  const int lane = tid & 63;
  const int wq = tid >> 6;
  const int bt = blockIdx.x >> 6;        // batch group 0..3
  const int gt = blockIdx.x & 63;        // j tile 0..63
  const int b0 = bt * MB;
  const int r0 = gt * NR;

  const int l15 = lane & 15;
  const int kqu = lane >> 4;             // 0..3 (16B unit within 32-k chunk)

  // ---- prologue: stage Wh k-units 0..119 -> Wl (two tmp[16] phases) ----
  {
    const int u = tid & 127;
    const bool act = u < WU;
    uint32x4 tmp[16];
#pragma unroll
    for (int q = 0; q < 16; ++q) {
      int row = q * 2 + (tid >> 7);
      if (act) tmp[q] = *reinterpret_cast<const uint32x4*>(
          Wp + (size_t)(r0 + row) * KTOT + II + u * 8);
    }
#pragma unroll
    for (int q = 0; q < 16; ++q) {
      int row = q * 2 + (tid >> 7);
      if (act) *reinterpret_cast<uint32x4*>(Wl + row * WROWB + ((u ^ (row & 7)) << 4)) = tmp[q];
    }
#pragma unroll
    for (int q = 0; q < 16; ++q) {
      int row = 32 + q * 2 + (tid >> 7);
      if (act) tmp[q] = *reinterpret_cast<const uint32x4*>(
          Wp + (size_t)(r0 + row) * KTOT + II + u * 8);
    }
#pragma unroll
    for (int q = 0; q < 16; ++q) {
      int row = 32 + q * 2 + (tid >> 7);
      if (act) *reinterpret_cast<uint32x4*>(Wl + row * WROWB + ((u ^ (row & 7)) << 4)) = tmp[q];
    }
  }

  // ---- wave's weights in registers: Wx (8 frags) + Wh tail units 120..127 ----
  const int brow = r0 + wq * 16 + l15;             // this lane's packed gate row
  bf16x8 wxr[8], wht0, wht1;
  {
    const __hip_bfloat16* ws = Wp + (size_t)brow * KTOT + kqu * 8;
#pragma unroll
    for (int kk = 0; kk < 8; ++kk)
      wxr[kk] = *reinterpret_cast<const bf16x8*>(ws + kk * 32);
    wht0 = *reinterpret_cast<const bf16x8*>(ws + II + 960);   // unit 120+kqu
    wht1 = *reinterpret_cast<const bf16x8*>(ws + II + 992);   // unit 124+kqu
  }

  // ---- epilogue cell identity: thread -> (b_l = m_e, j_l = wq*4+tq) ----
  const int m_e = 4 * kqu + (lane & 3);            // batch 0..15
  const int tq = (lane >> 2) & 3;                  // j offset within wave
  const int j_g = gt * NJ + wq * 4 + tq;
  const int b_g = b0 + m_e;
  const float4 bias = *reinterpret_cast<const float4*>(biasp + j_g * 4);
  float c_reg = c0[(size_t)b_g * HH + j_g];

  // ---- fragment geometry ----
  const int hs_swz = l15 & 7;                      // A rows: batch = l15
  const int bn_row = wq * 16 + l15;                // B rows: wave's Wl rows
  const int bn_swz = bn_row & 7;
  char* ZxW = Zx + wq * 1280;
  char* HoW = Ho + wq * 128;

  // ---- prologue: per-wave stage h(0) rows [wq*4,+4), coalesced sc1 ----
  {
    uint32x4 tmp[8];
#pragma unroll
    for (int q = 0; q < 8; ++q) {
      int idx = q * 64 + lane;                     // 0..511
      int rl = wq * 4 + (idx >> 7);
      int u = idx & 127;
      tmp[q] = ld16_sc1(hbuf + (size_t)(b0 + rl) * HH + u * 8);
    }
    asm volatile("s_waitcnt vmcnt(0)" ::: "memory");
    __builtin_amdgcn_sched_barrier(0);
#pragma unroll
    for (int q = 0; q < 8; ++q) {
      int idx = q * 64 + lane;
      int rl = wq * 4 + (idx >> 7);
      int u = idx & 127;
      *reinterpret_cast<uint32x4*>(Hs + rl * HROWB + ((u ^ (rl & 7)) << 4)) = tmp[q];
    }
  }

  // ---- prologue: x-part MFMA for t=0 ----
  const __hip_bfloat16* xrowA = xb + (size_t)(b0 + l15) * (TT * II) + kqu * 8;
  f32x4 accs[4];
#pragma unroll
  for (int q = 0; q < 4; ++q) accs[q] = (f32x4){0.f, 0.f, 0.f, 0.f};
#pragma unroll
  for (int kk = 0; kk < 8; ++kk) {
    bf16x8 xa = *reinterpret_cast<const bf16x8*>(xrowA + kk * 32);
    accs[kk & 3] = __builtin_amdgcn_mfma_f32_16x16x32_bf16(xa, wxr[kk], accs[kk & 3], 0, 0, 0);
  }

  __syncthreads();

  for (int t = 0; t < TT; ++t) {
    // ---- A: h-part MFMA (x-part already in accs) ----
#pragma unroll
    for (int kk = 0; kk < 30; ++kk) {
      int u = kk * 4 + kqu;
      bf16x8 a = *reinterpret_cast<const bf16x8*>(Hs + l15 * HROWB + ((u ^ hs_swz) << 4));
      bf16x8 b = *reinterpret_cast<const bf16x8*>(Wl + bn_row * WROWB + ((u ^ bn_swz) << 4));
      accs[kk & 3] = __builtin_amdgcn_mfma_f32_16x16x32_bf16(a, b, accs[kk & 3], 0, 0, 0);
    }
    {
      int u = 120 + kqu;
      bf16x8 a = *reinterpret_cast<const bf16x8*>(Hs + l15 * HROWB + ((u ^ hs_swz) << 4));
      accs[2] = __builtin_amdgcn_mfma_f32_16x16x32_bf16(a, wht0, accs[2], 0, 0, 0);
    }
    {
      int u = 124 + kqu;
      bf16x8 a = *reinterpret_cast<const bf16x8*>(Hs + l15 * HROWB + ((u ^ hs_swz) << 4));
      accs[3] = __builtin_amdgcn_mfma_f32_16x16x32_bf16(a, wht1, accs[3], 0, 0, 0);
    }
    f32x4 acc = (accs[0] + accs[1]) + (accs[2] + accs[3]);

    // ---- B: in-wave z exchange via LDS (drains step-A LDS reads too) ----
    *reinterpret_cast<f32x4*>(ZxW + l15 * 80 + kqu * 16) = acc;
    asm volatile("s_waitcnt lgkmcnt(0)" ::: "memory");
    __builtin_amdgcn_sched_barrier(0);
    float zi = *reinterpret_cast<const float*>(ZxW + (4 * tq + 0) * 80 + m_e * 4) + bias.x;
    float zf = *reinterpret_cast<const float*>(ZxW + (4 * tq + 1) * 80 + m_e * 4) + bias.y;
    float zg = *reinterpret_cast<const float*>(ZxW + (4 * tq + 2) * 80 + m_e * 4) + bias.z;
    float zo = *reinterpret_cast<const float*>(ZxW + (4 * tq + 3) * 80 + m_e * 4) + bias.w;

    float ig = 1.f / (1.f + __expf(-zi));
    float fg = 1.f / (1.f + __expf(-zf));
    float gg = 2.f / (1.f + __expf(-2.f * zg)) - 1.f;
    float og = 1.f / (1.f + __expf(-zo));
    c_reg = fg * c_reg + ig * gg;
    float tc = 2.f / (1.f + __expf(-2.f * c_reg)) - 1.f;
    float h = og * tc;

    if (t == TT - 1) {
      out[(size_t)b_g * (TT * HH) + (size_t)t * HH + j_g] = h;
      out[(size_t)BB * TT * HH + (size_t)b_g * HH + j_g] = h;
      out[(size_t)BB * TT * HH + BB * HH + (size_t)b_g * HH + j_g] = c_reg;
      break;
    }

    // ---- C: h -> wave-local Ho bounce, publish 8B sc1, per-wave flag ----
    __hip_bfloat16 hb16 = __float2bfloat16(h);
    *reinterpret_cast<unsigned short*>(HoW + m_e * 8 + tq * 2) =
        *reinterpret_cast<unsigned short*>(&hb16);
    asm volatile("s_waitcnt lgkmcnt(0)" ::: "memory");
    __builtin_amdgcn_sched_barrier(0);

    const int nxt = (t + 1) & 1;
    if (lane < 16) {
      uint32x2 hv = *reinterpret_cast<const uint32x2*>(HoW + lane * 8);
      __hip_bfloat16* dst = hbuf + (size_t)nxt * (BB * HH)
                          + (size_t)(b0 + lane) * HH + gt * NJ + wq * 4;
      asm volatile("global_store_dwordx2 %0, %1, off sc1" :: "v"(dst), "v"(hv) : "memory");
    }
    asm volatile("s_waitcnt vmcnt(0)" ::: "memory");
    if (lane == 0) {
      unsigned gen = (unsigned)t + 1u;
      asm volatile("global_store_dword %0, %1, off sc1"
                   :: "v"(flags + bt * 256 + gt * 4 + wq), "v"(gen) : "memory");
    }

    // ---- D: poll-window work: out store + x(t+1)-part MFMA ----
    out[(size_t)b_g * (TT * HH) + (size_t)t * HH + j_g] = h;
#pragma unroll
    for (int q = 0; q < 4; ++q) accs[q] = (f32x4){0.f, 0.f, 0.f, 0.f};
    {
      const __hip_bfloat16* xp = xrowA + (size_t)(t + 1) * II;
#pragma unroll
      for (int kk = 0; kk < 8; ++kk) {
        bf16x8 xa = *reinterpret_cast<const bf16x8*>(xp + kk * 32);
        accs[kk & 3] = __builtin_amdgcn_mfma_f32_16x16x32_bf16(xa, wxr[kk], accs[kk & 3], 0, 0, 0);
      }
    }

    // ---- E: every wave polls its group's 256 flags (4 per lane) ----
    {
      const unsigned target = (unsigned)t + 1u;
      const unsigned* fp = flags + bt * 256 + lane * 4;
      uint32x4 f;
      int ok;
      do {
        asm volatile("global_load_dwordx4 %0, %1, off sc1\n\ts_waitcnt vmcnt(0)"
                     : "=&v"(f) : "v"(fp) : "memory");
        ok = (f.x >= target) && (f.y >= target) && (f.z >= target) && (f.w >= target);
      } while (!__all(ok));
    }

    // ---- F: per-wave stage h(t+1) rows [wq*4,+4), coalesced sc1 ----
    {
      uint32x4 tmp[8];
      const __hip_bfloat16* hsrc = hbuf + (size_t)nxt * (BB * HH);
#pragma unroll
      for (int q = 0; q < 8; ++q) {
        int idx = q * 64 + lane;
        int rl = wq * 4 + (idx >> 7);
        int u = idx & 127;
        tmp[q] = ld16_sc1(hsrc + (size_t)(b0 + rl) * HH + u * 8);
      }
      asm volatile("s_waitcnt vmcnt(0)" ::: "memory");
      __builtin_amdgcn_sched_barrier(0);
#pragma unroll
      for (int q = 0; q < 8; ++q) {
        int idx = q * 64 + lane;
        int rl = wq * 4 + (idx >> 7);
        int u = idx & 127;
        *reinterpret_cast<uint32x4*>(Hs + rl * HROWB + ((u ^ (rl & 7)) << 4)) = tmp[q];
      }
    }
    __syncthreads();                     // stage -> fragment-read handoff
  }
}

// ---------------- launcher ----------------

extern "C" void kernel_launch(void* const* d_in, const int* in_sizes, int n_in,
                              void* d_out, int out_size, void* d_ws, size_t ws_size,
                              hipStream_t stream) {
  (void)in_sizes; (void)n_in; (void)out_size; (void)ws_size;
  const float* inputs = (const float*)d_in[0];
  const float* h0 = (const float*)d_in[1];
  const float* c0 = (const float*)d_in[2];
  const float* w_ii = (const float*)d_in[3];
  const float* w_hi = (const float*)d_in[4];
  const float* b_ii = (const float*)d_in[5];
  const float* b_hi = (const float*)d_in[6];
  const float* w_if = (const float*)d_in[7];
  const float* w_hf = (const float*)d_in[8];
  const float* b_if = (const float*)d_in[9];
  const float* b_hf = (const float*)d_in[10];
  const float* w_io = (const float*)d_in[11];
  const float* w_ho = (const float*)d_in[12];
  const float* b_io = (const float*)d_in[13];
  const float* b_ho = (const float*)d_in[14];
  const float* w_ig = (const float*)d_in[15];
  const float* w_hg = (const float*)d_in[16];
  const float* b_ig = (const float*)d_in[17];
  const float* b_hg = (const float*)d_in[18];

  char* ws = (char*)d_ws;
  __hip_bfloat16* xb    = (__hip_bfloat16*)ws;                    // 16,777,216 B
  __hip_bfloat16* Wp    = (__hip_bfloat16*)(ws + 16777216);       // 10,485,760 B
  float*          biasp = (float*)(ws + 27262976);                // 16,384 B
  __hip_bfloat16* hbuf  = (__hip_bfloat16*)(ws + 27279360);       // 262,144 B
  unsigned*       flags = (unsigned*)(ws + 27541504);             // 4,096 B
  float* out = (float*)d_out;

  k_cast_inputs<<<8192, 256, 0, stream>>>(inputs, xb);
  k_pack_w<<<5120, 256, 0, stream>>>(w_ii, w_hi, w_if, w_hf, w_ig, w_hg, w_io, w_ho, Wp);
  k_pack_bias_h0<<<256, 256, 0, stream>>>(b_ii, b_hi, b_if, b_hf, b_ig, b_hg,
                                          b_io, b_ho, h0, biasp, hbuf, flags);

  const int lds_bytes = 161280;
  hipFuncSetAttribute((const void*)k_lstm,
                      hipFuncAttributeMaxDynamicSharedMemorySize, lds_bytes);
  void* args[] = {(void*)&xb, (void*)&Wp, (void*)&biasp, (void*)&c0,
                  (void*)&hbuf, (void*)&flags, (void*)&out};
  hipLaunchCooperativeKernel((void*)k_lstm, dim3(NWG), dim3(256), args,
                             lds_bytes, stream);
}